// Round 14
// baseline (2063.549 us; speedup 1.0000x reference)
//
#include <hip/hip_runtime.h>
#include <math.h>

#define B_    64
#define T_    512
#define EMB_  128
#define E_    256
#define H_    384
#define K_    13
#define NBG   4       // batch groups (16 batches each)
#define NG    6       // unit groups (64 units each)
#define NW    8       // waves per block
#define XROWB 1296    // Xs row stride bytes (648 shorts; 640 used; 2-way bank alias = free)

typedef short s8v __attribute__((ext_vector_type(8)));
typedef short s4v __attribute__((ext_vector_type(4)));
typedef float f4v __attribute__((ext_vector_type(4)));
typedef unsigned long long ull;

__device__ __forceinline__ float sigm(float x){ return 1.f/(1.f+__expf(-x)); }
__device__ __forceinline__ float tanh_f(float x){ return 2.f/(1.f+__expf(-2.f*x)) - 1.f; }
__device__ __forceinline__ short f2bf(float x){
  unsigned u = __builtin_bit_cast(unsigned, x);
  return (short)((u + 0x7FFFu + ((u>>16)&1u)) >> 16);
}
__device__ __forceinline__ float bf2f(short s){
  return __builtin_bit_cast(float, ((unsigned)(unsigned short)s) << 16);
}
// producer-slice-major: [par][dir][bg][g][b][64u] u32
__device__ __forceinline__ size_t hslot(int par, int dir, int bg){
  return (size_t)(((par*2 + dir)*NBG + bg)) * (NG*16*64);
}
// raw workgroup barrier: waits LDS ops only; global ops stay in flight
#define LBAR() do{ __builtin_amdgcn_sched_barrier(0); \
  asm volatile("s_waitcnt lgkmcnt(0)" ::: "memory"); \
  __builtin_amdgcn_s_barrier(); \
  __builtin_amdgcn_sched_barrier(0); }while(0)

// ---------- K0: pack weights into per-lane MFMA A-fragments (bf16), gate-major rows,
// h-K rotated by g*64 so each block's own units sit at kt 8..9. (verified r8-r13, absmax 0)
__global__ __launch_bounds__(256) void k_packA(
    const float* __restrict__ wih_f, const float* __restrict__ whh_f,
    const float* __restrict__ wih_b, const float* __restrict__ whh_b,
    s8v* __restrict__ Apack)
{
  int idx = blockIdx.x*256 + threadIdx.x;          // 0..245759
  if (idx >= 12*NW*2*20*64) return;
  int l   = idx & 63;
  int f   = idx >> 6;
  int kt  = f % 20;
  int rt  = (f/20) & 1;
  int w   = (f/40) % NW;
  int set = f/(40*NW);
  int g   = set % NG, dir = set / NG;
  const float* wih = dir ? wih_b : wih_f;
  const float* whh = dir ? whh_b : whh_f;
  int pr = l & 15;
  int R  = (pr&3)*H_ + g*64 + (w*8 + rt*4 + (pr>>2));
  int kb = kt*32 + (l>>4)*8;
  const float* src;
  if (kb < E_) src = wih + (size_t)R*E_ + kb;
  else         src = whh + (size_t)R*H_ + ((g*64 + kb - E_) % H_);
  s8v out;
  #pragma unroll
  for (int e = 0; e < 8; e++) out[e] = f2bf(src[e]);
  Apack[idx] = out;
}

// ---------- K1: gather embeddings -> X_all[t][b][256] bf16
__global__ __launch_bounds__(256) void k_embX(
    const int* __restrict__ char_id, const int* __restrict__ bichar_id,
    const float* __restrict__ char_table, const float* __restrict__ bichar_table,
    short* __restrict__ X_all)
{
  int rid  = blockIdx.x*4 + (threadIdx.x>>6);
  int lane = threadIdx.x & 63;
  int t = rid >> 6, b = rid & 63;
  float4 v;
  if (lane < 32) { int c = char_id  [b*T_ + t]; v = *(const float4*)(char_table  + (size_t)c*EMB_ + lane*4); }
  else           { int c = bichar_id[b*T_ + t]; v = *(const float4*)(bichar_table+ (size_t)c*EMB_ + (lane-32)*4); }
  s4v o; o[0]=f2bf(v.x); o[1]=f2bf(v.y); o[2]=f2bf(v.z); o[3]=f2bf(v.w);
  *(s4v*)(X_all + ((size_t)rid*E_ + lane*4)) = o;
}

// ---------- K2: persistent-weight MFMA LSTM; XCD-LOCAL exchange with RUNTIME role claim.
// 256 blocks launched; each reads its physical XCD (s_getreg HW_REG_XCC_ID), claims one
// of 6 unit-group roles for the chain pinned to that XCD (dir=xcd&1, bg=xcd>>1); surplus
// blocks exit. All 6 peers of a chain are provably co-XCD -> h exchange goes through the
// SHARED per-XCD L2: producers publish with plain (workgroup-scope) stores, consumers
// poll with sc0 (L1-bypass) loads. Agent-scope mirror + sticky escalation after 64
// misses keeps any mapping/semantics failure correct (r13-speed), never hanging.
__global__ __launch_bounds__(512, 2) void k_lstm_p(
    const s8v* __restrict__ Apack,
    const short* __restrict__ X_all,
    const float* __restrict__ b_f, const float* __restrict__ b_b,
    const float* __restrict__ w_em,
    unsigned* __restrict__ h_fast,      // [2][dir][bg][g][16 b][64 u] u32=(bf16<<16)|t
    unsigned* __restrict__ h_safe,      // agent-scope mirror, same layout
    int* __restrict__ claim,            // [8] role counters per XCD, zeroed each launch
    short* __restrict__ em16)           // [48 pb][512 t][16 b][13 k] bf16
{
  __shared__ char  Xsb[16*XROWB];       // B operand rows=batch: x 0..255, h(rotated) 256..639
  __shared__ short hsl[16][66];         // new h [b][uo]
  __shared__ float wems[K_][64];
  __shared__ int   roleSh[2];

  const int tid = threadIdx.x, lane = tid & 63, w = tid >> 6;

  // ---- runtime role claim
  if (tid == 0) {
    unsigned xcc;
    asm volatile("s_getreg_b32 %0, hwreg(HW_REG_XCC_ID)" : "=s"(xcc));
    int chain = (int)(xcc & 7u);
    int idx = atomicAdd(&claim[chain], 1);
    roleSh[0] = chain; roleSh[1] = idx;
  }
  __syncthreads();
  const int chain = roleSh[0], ridx = roleSh[1];
  if (ridx >= NG) return;               // surplus block: exit
  const int dir = chain & 1, bg = chain >> 1, g = ridx;
  const int pb  = (dir*NBG+bg)*NG + g;

  // persistent A fragments: 40 s8v = 160 regs (unified VGPR/AGPR file)
  s8v fr0[20], fr1[20];
  {
    const s8v* ap = Apack + ((size_t)((dir*NG+g)*NW + w)*40)*64 + lane;
    #pragma unroll
    for (int kt = 0; kt < 20; kt++) fr0[kt] = ap[kt*64];
    #pragma unroll
    for (int kt = 0; kt < 20; kt++) fr1[kt] = ap[(20+kt)*64];
  }
  for (int i = tid; i < K_*64; i += 512)
    wems[i>>6][i&63] = w_em[(size_t)(i>>6)*(2*H_) + dir*H_ + g*64 + (i&63)];

  const int batch = lane & 15;
  const int uA = w*8 + (lane>>4), uB = uA + 4;    // unit offsets in [0,64)
  const float* bias = dir ? b_b : b_f;
  float bA[4], bB[4];
  #pragma unroll
  for (int r = 0; r < 4; r++) { bA[r] = bias[r*H_ + g*64 + uA]; bB[r] = bias[r*H_ + g*64 + uB]; }
  float cA = 0.f, cB = 0.f;

  const int b_x = tid>>5, kox = (tid&31)*8;       // x-store ownership
  const int b_r = tid>>5, ch = tid&31;            // burst: u64 #ch of row (peer, b_r)
  int poff[5];                                    // h buffer u32 offset of each peer's word
  int posb[5];                                    // rotated Xs position base of each peer
  #pragma unroll
  for (int i = 0; i < 5; i++) {
    int p = (g + 1 + i) % NG;                     // the 5 remote peers
    poff[i] = (p*16 + b_r)*64 + ch*2;
    posb[i] = ((p - g + NG) % NG) * 64 + ch*2;    // in [64, 384)
  }
  bool useSafe = false;

  // zero h region (used at s==0)
  for (int cc = tid; cc < 16*192; cc += 512)
    *(unsigned*)(Xsb + (cc/192)*XROWB + 512 + (cc%192)*4) = 0u;

  s8v xv = *(const s8v*)(X_all + ((size_t)((dir?(T_-1):0)*B_ + bg*16 + b_x)*E_ + kox));
  __syncthreads();

  for (int s = 0; s < T_; s++) {
    const int t  = dir ? (T_-1-s) : s;
    const int tp = dir ? t+1 : t-1;
    const int tn = dir ? t-1 : t+1;

    // 1. store prefetched x(t); prefetch x(next)
    *(s8v*)(Xsb + b_x*XROWB + 2*kox) = xv;
    if (s+1 < T_) xv = *(const s8v*)(X_all + ((size_t)(tn*B_ + bg*16 + b_x)*E_ + kox));

    LBAR();                                       // barrier A

    // 2. emission for previous step (local; reads hsl = h(tp))
    if (s > 0) {
      for (int k = w; k < K_; k += NW) {
        int b = lane>>2, cq = lane&3;
        float acc = 0.f;
        #pragma unroll
        for (int m = 0; m < 8; m++) {
          int u = cq*16 + 2*m;
          unsigned pr = *(const unsigned*)&hsl[b][u];
          acc += bf2f((short)(pr & 0xFFFF)) * wems[k][u]
               + bf2f((short)(pr >> 16))    * wems[k][u+1];
        }
        acc += __shfl_xor(acc, 1, 64);
        acc += __shfl_xor(acc, 2, 64);
        if (cq == 0) em16[((size_t)(pb*T_ + tp)*16 + b)*K_ + k] = f2bf(acc);
      }
    }

    // 3. B1: x (kt 0..7) + own h (kt 8..9) — covers peers' store-travel window
    f4v a0 = {0.f,0.f,0.f,0.f}, a1 = a0;
    #pragma unroll
    for (int kt = 0; kt < 10; kt++) {
      s8v bq = *(const s8v*)(Xsb + (lane&15)*XROWB + kt*64 + (lane>>4)*16);
      a0 = __builtin_amdgcn_mfma_f32_16x16x32_bf16(fr0[kt], bq, a0, 0,0,0);
      a1 = __builtin_amdgcn_mfma_f32_16x16x32_bf16(fr1[kt], bq, a1, 0,0,0);
    }

    // 4. burst: 5 coalesced tagged u64 loads; fast path via shared XCD L2 (sc0),
    //    sticky escalation to agent-scope mirror after 64 misses
    if (s > 0) {
      const unsigned tag = (unsigned)(tp & 0xFFFF);
      const ull tagpair = (ull)tag | ((ull)tag << 32);
      const unsigned* fb = h_fast + hslot(tp&1, dir, bg);
      const unsigned* sb = h_safe + hslot(tp&1, dir, bg);
      ull v0, v1, v2, v3, v4;
      int tr = 0;
      while (true) {
        if (!useSafe) {
          asm volatile(
            "global_load_dwordx2 %0, %5, off sc0\n\t"
            "global_load_dwordx2 %1, %6, off sc0\n\t"
            "global_load_dwordx2 %2, %7, off sc0\n\t"
            "global_load_dwordx2 %3, %8, off sc0\n\t"
            "global_load_dwordx2 %4, %9, off sc0\n\t"
            "s_waitcnt vmcnt(0)"
            : "=v"(v0), "=v"(v1), "=v"(v2), "=v"(v3), "=v"(v4)
            : "v"((const ull*)(fb + poff[0])), "v"((const ull*)(fb + poff[1])),
              "v"((const ull*)(fb + poff[2])), "v"((const ull*)(fb + poff[3])),
              "v"((const ull*)(fb + poff[4]))
            : "memory");
        } else {
          v0 = __hip_atomic_load((const ull*)(sb + poff[0]), __ATOMIC_RELAXED, __HIP_MEMORY_SCOPE_AGENT);
          v1 = __hip_atomic_load((const ull*)(sb + poff[1]), __ATOMIC_RELAXED, __HIP_MEMORY_SCOPE_AGENT);
          v2 = __hip_atomic_load((const ull*)(sb + poff[2]), __ATOMIC_RELAXED, __HIP_MEMORY_SCOPE_AGENT);
          v3 = __hip_atomic_load((const ull*)(sb + poff[3]), __ATOMIC_RELAXED, __HIP_MEMORY_SCOPE_AGENT);
          v4 = __hip_atomic_load((const ull*)(sb + poff[4]), __ATOMIC_RELAXED, __HIP_MEMORY_SCOPE_AGENT);
        }
        ull m = (v0^tagpair) | (v1^tagpair) | (v2^tagpair) | (v3^tagpair) | (v4^tagpair);
        if ((m & 0x0000FFFF0000FFFFull) == 0ull) break;
        ++tr;
        if (tr > 64) useSafe = true;              // sticky escalation (G16 safety)
        if (tr > 16) __builtin_amdgcn_s_sleep(1);
      }
      ull vv[5] = {v0, v1, v2, v3, v4};
      #pragma unroll
      for (int i = 0; i < 5; i++) {
        unsigned lo = (unsigned)vv[i], hi = (unsigned)(vv[i] >> 32);
        *(unsigned*)(Xsb + b_r*XROWB + 512 + posb[i]*2) = (lo >> 16) | (hi & 0xFFFF0000u);
      }
    }
    LBAR();                                       // barrier B

    // 5. B2: remote h (kt 10..19)
    #pragma unroll
    for (int kt = 10; kt < 20; kt++) {
      s8v bq = *(const s8v*)(Xsb + (lane&15)*XROWB + kt*64 + (lane>>4)*16);
      a0 = __builtin_amdgcn_mfma_f32_16x16x32_bf16(fr0[kt], bq, a0, 0,0,0);
      a1 = __builtin_amdgcn_mfma_f32_16x16x32_bf16(fr1[kt], bq, a1, 0,0,0);
    }

    // 6. C: in-register nonlinearity (acc[r] = gate r), dual publish, own-h -> Xs/hsl
    {
      cA = sigm(a0[1]+bA[1])*cA + sigm(a0[0]+bA[0])*tanh_f(a0[2]+bA[2]);
      float h0 = sigm(a0[3]+bA[3])*tanh_f(cA);
      cB = sigm(a1[1]+bB[1])*cB + sigm(a1[0]+bB[0])*tanh_f(a1[2]+bB[2]);
      float h1 = sigm(a1[3]+bB[3])*tanh_f(cB);
      short hb0 = f2bf(h0), hb1 = f2bf(h1);
      unsigned vt = (unsigned)(t & 0xFFFF);
      unsigned q0 = ((unsigned)(unsigned short)hb0 << 16) | vt;
      unsigned q1 = ((unsigned)(unsigned short)hb1 << 16) | vt;
      size_t off = hslot(t&1, dir, bg) + (size_t)(g*16 + batch)*64;
      // fast: plain (workgroup-scope) stores -> stay in shared XCD L2
      __hip_atomic_store(h_fast + off + uA, q0, __ATOMIC_RELAXED, __HIP_MEMORY_SCOPE_WORKGROUP);
      __hip_atomic_store(h_fast + off + uB, q1, __ATOMIC_RELAXED, __HIP_MEMORY_SCOPE_WORKGROUP);
      // safe: agent-scope mirror
      __hip_atomic_store(h_safe + off + uA, q0, __ATOMIC_RELAXED, __HIP_MEMORY_SCOPE_AGENT);
      __hip_atomic_store(h_safe + off + uB, q1, __ATOMIC_RELAXED, __HIP_MEMORY_SCOPE_AGENT);
      *(short*)(Xsb + batch*XROWB + 512 + uA*2) = hb0;   // own units = rotated pos 0..63
      *(short*)(Xsb + batch*XROWB + 512 + uB*2) = hb1;
      hsl[batch][uA] = hb0;
      hsl[batch][uB] = hb1;
    }
    // no drain, no flag: stores travel while we loop; consumers tag-verify the data
  }

  // final emission for last step's h
  LBAR();
  {
    const int tl = dir ? 0 : T_-1;
    for (int k = w; k < K_; k += NW) {
      int b = lane>>2, cq = lane&3;
      float acc = 0.f;
      #pragma unroll
      for (int m = 0; m < 8; m++) {
        int u = cq*16 + 2*m;
        unsigned pr = *(const unsigned*)&hsl[b][u];
        acc += bf2f((short)(pr & 0xFFFF)) * wems[k][u]
             + bf2f((short)(pr >> 16))    * wems[k][u+1];
      }
      acc += __shfl_xor(acc, 1, 64);
      acc += __shfl_xor(acc, 2, 64);
      if (cq == 0) em16[((size_t)(pb*T_ + tl)*16 + b)*K_ + k] = f2bf(acc);
    }
  }
}

// ---------- K3: combine 12 partials + bias, log_softmax -> em_out
__global__ __launch_bounds__(256) void k_em2(
    const short* __restrict__ em16, const float* __restrict__ b_em,
    float* __restrict__ em)
{
  int r = blockIdx.x*256 + threadIdx.x;           // b*512 + t
  int b = r >> 9, t = r & 511;
  int bg = b >> 4, b16 = b & 15;
  float e[K_];
  #pragma unroll
  for (int k = 0; k < K_; k++) e[k] = b_em[k];
  #pragma unroll
  for (int dir = 0; dir < 2; dir++)
    for (int g = 0; g < NG; g++) {
      int pb = (dir*NBG+bg)*NG + g;
      const short* p = em16 + ((size_t)(pb*T_ + t)*16 + b16)*K_;
      #pragma unroll
      for (int k = 0; k < K_; k++) e[k] += bf2f(p[k]);
    }
  float mx = -1e30f;
  #pragma unroll
  for (int k = 0; k < K_; k++) mx = fmaxf(mx, e[k]);
  float S = 0.f;
  #pragma unroll
  for (int k = 0; k < K_; k++) S += __expf(e[k]-mx);
  float L = __logf(S) + mx;
  #pragma unroll
  for (int k = 0; k < K_; k++) em[(size_t)r*K_+k] = e[k] - L;
}

// ---------- K4: CRF gold score + forward algorithm
__global__ __launch_bounds__(64) void k_crf(
    const int* __restrict__ char_id, const int* __restrict__ label_id,
    const float* __restrict__ em,
    const float* __restrict__ start_trans, const float* __restrict__ end_trans,
    const float* __restrict__ trans, float* __restrict__ llh)
{
  int b = blockIdx.x, lane = threadIdx.x;
  const int*   cid = char_id  + b*T_;
  const int*   tag = label_id + b*T_;
  const float* emb = em + (size_t)b*T_*K_;

  float sc = 0.f; int cntm = 0;
  for (int t = lane; t < T_; t += 64) {
    int m = (cid[t] != 0);
    cntm += m;
    if (t >= 1 && m) sc += trans[tag[t-1]*K_ + tag[t]] + emb[t*K_ + tag[t]];
  }
  #pragma unroll
  for (int off = 32; off; off >>= 1) { sc += __shfl_xor(sc, off, 64); cntm += __shfl_xor(cntm, off, 64); }

  __shared__ float alpha[K_];
  __shared__ float scoreSh;
  if (lane == 0) {
    int t0 = tag[0];
    int ce = (cntm > 0) ? (cntm - 1) : 0;
    scoreSh = start_trans[t0] + emb[t0] + sc + end_trans[tag[ce]];
  }
  if (lane < K_) alpha[lane] = start_trans[lane] + emb[lane];
  float tr[K_];
  if (lane < K_) {
    #pragma unroll
    for (int i = 0; i < K_; i++) tr[i] = trans[i*K_ + lane];
  }
  __syncthreads();

  for (int t = 1; t < T_; t++) {
    bool mt = (cid[t] != 0);
    float nxt = 0.f;
    if (lane < K_) {
      float a[K_];
      #pragma unroll
      for (int i = 0; i < K_; i++) a[i] = alpha[i] + tr[i];
      float m = a[0];
      #pragma unroll
      for (int i = 1; i < K_; i++) m = fmaxf(m, a[i]);
      float s2 = 0.f;
      #pragma unroll
      for (int i = 0; i < K_; i++) s2 += __expf(a[i]-m);
      nxt = m + __logf(s2) + emb[t*K_ + lane];
    }
    __syncthreads();
    if (lane < K_ && mt) alpha[lane] = nxt;
    __syncthreads();
  }

  if (lane == 0) {
    float m = alpha[0] + end_trans[0];
    #pragma unroll
    for (int k = 1; k < K_; k++) m = fmaxf(m, alpha[k]+end_trans[k]);
    float s2 = 0.f;
    #pragma unroll
    for (int k = 0; k < K_; k++) s2 += __expf(alpha[k]+end_trans[k]-m);
    llh[b] = scoreSh - (m + __logf(s2));
  }
}

// ---------- K5: out = -mean(llh)
__global__ __launch_bounds__(64) void k_final(const float* __restrict__ llh, float* __restrict__ out){
  float v = llh[threadIdx.x];
  #pragma unroll
  for (int off = 32; off; off >>= 1) v += __shfl_xor(v, off, 64);
  if (threadIdx.x == 0) out[0] = -v / (float)B_;
}

extern "C" void kernel_launch(void* const* d_in, const int* in_sizes, int n_in,
                              void* d_out, int out_size, void* d_ws, size_t ws_size,
                              hipStream_t stream)
{
  const int*   char_id      = (const int*)  d_in[0];
  const int*   bichar_id    = (const int*)  d_in[1];
  const int*   label_id     = (const int*)  d_in[2];
  const float* char_table   = (const float*)d_in[3];
  const float* bichar_table = (const float*)d_in[4];
  const float* w_ih_f       = (const float*)d_in[5];
  const float* w_hh_f       = (const float*)d_in[6];
  const float* b_f          = (const float*)d_in[7];
  const float* w_ih_b       = (const float*)d_in[8];
  const float* w_hh_b       = (const float*)d_in[9];
  const float* b_b          = (const float*)d_in[10];
  const float* w_em         = (const float*)d_in[11];
  const float* b_em         = (const float*)d_in[12];
  const float* start_trans  = (const float*)d_in[13];
  const float* end_trans    = (const float*)d_in[14];
  const float* trans        = (const float*)d_in[15];

  char* w = (char*)d_ws;
  s8v*      Apack  = (s8v*)w;      w += (size_t)12*NW*2*20*64*16;    //  3,932,160
  short*    X_all  = (short*)w;    w += (size_t)T_*B_*E_*2;          // 16,777,216
  unsigned* h_fast = (unsigned*)w; w += (size_t)2*2*NBG*NG*16*64*4;  //    393,216
  unsigned* h_safe = (unsigned*)w; w += (size_t)2*2*NBG*NG*16*64*4;  //    393,216
  int*      claim  = (int*)w;      w += 512;
  short*    em16   = (short*)w;    w += (size_t)48*T_*16*K_*2;       // 10,223,616
  float*    em_out = (float*)w;    w += (size_t)B_*T_*K_*4;          //  1,703,936
  float*    llh    = (float*)w;    w += 256;
  // total ~33.4 MB

  // init: h buffers to 0xFF (invalid tags), claim counters to 0
  hipMemsetAsync(h_fast, 0xFF, (size_t)2 * (2*2*NBG*NG*16*64*4), stream);
  hipMemsetAsync(claim, 0, 512, stream);

  k_packA<<<960, 256, 0, stream>>>(w_ih_f, w_hh_f, w_ih_b, w_hh_b, Apack);
  k_embX <<<8192, 256, 0, stream>>>(char_id, bichar_id, char_table, bichar_table, X_all);
  k_lstm_p<<<256, 512, 0, stream>>>(Apack, X_all, b_f, b_b, w_em, h_fast, h_safe, claim, em16);
  k_em2  <<<128, 256, 0, stream>>>(em16, b_em, em_out);
  k_crf  <<<64, 64, 0, stream>>>(char_id, label_id, em_out, start_trans, end_trans, trans, llh);
  k_final<<<1, 64, 0, stream>>>(llh, (float*)d_out);
}

// Round 15
// 1602.576 us; speedup vs baseline: 1.2876x; 1.2876x over previous
//
#include <hip/hip_runtime.h>
#include <math.h>

#define B_    64
#define T_    512
#define EMB_  128
#define E_    256
#define H_    384
#define K_    13
#define NBG   4       // batch groups (16 batches each)
#define NG    6       // unit groups (64 units each)
#define NW    8       // waves per block
#define XROWB 1296    // Xs row stride bytes (648 shorts; 640 used; 2-way bank alias = free)

typedef short s8v __attribute__((ext_vector_type(8)));
typedef short s4v __attribute__((ext_vector_type(4)));
typedef float f4v __attribute__((ext_vector_type(4)));
typedef unsigned long long ull;

__device__ __forceinline__ float sigm(float x){ return 1.f/(1.f+__expf(-x)); }
__device__ __forceinline__ float tanh_f(float x){ return 2.f/(1.f+__expf(-2.f*x)) - 1.f; }
__device__ __forceinline__ short f2bf(float x){
  unsigned u = __builtin_bit_cast(unsigned, x);
  return (short)((u + 0x7FFFu + ((u>>16)&1u)) >> 16);
}
__device__ __forceinline__ float bf2f(short s){
  return __builtin_bit_cast(float, ((unsigned)(unsigned short)s) << 16);
}
// unit-major h layout: [par][dir][bg][u=g*64+uo][16 b] u32  (producer-coalesced)
__device__ __forceinline__ size_t hslot(int par, int dir, int bg){
  return (size_t)(((par*2 + dir)*NBG + bg)) * (NG*64*16);
}
// raw workgroup barrier: waits LDS ops only; global ops stay in flight
#define LBAR() do{ __builtin_amdgcn_sched_barrier(0); \
  asm volatile("s_waitcnt lgkmcnt(0)" ::: "memory"); \
  __builtin_amdgcn_s_barrier(); \
  __builtin_amdgcn_sched_barrier(0); }while(0)

// ---------- K0: pack weights into per-lane MFMA A-fragments (bf16), gate-major rows,
// h-K rotated by g*64 so each block's own units sit at kt 8..9. (verified r8-r14, absmax 0)
__global__ __launch_bounds__(256) void k_packA(
    const float* __restrict__ wih_f, const float* __restrict__ whh_f,
    const float* __restrict__ wih_b, const float* __restrict__ whh_b,
    s8v* __restrict__ Apack)
{
  int idx = blockIdx.x*256 + threadIdx.x;          // 0..245759
  if (idx >= 12*NW*2*20*64) return;
  int l   = idx & 63;
  int f   = idx >> 6;
  int kt  = f % 20;
  int rt  = (f/20) & 1;
  int w   = (f/40) % NW;
  int set = f/(40*NW);
  int g   = set % NG, dir = set / NG;
  const float* wih = dir ? wih_b : wih_f;
  const float* whh = dir ? whh_b : whh_f;
  int pr = l & 15;
  int R  = (pr&3)*H_ + g*64 + (w*8 + rt*4 + (pr>>2));
  int kb = kt*32 + (l>>4)*8;
  const float* src;
  if (kb < E_) src = wih + (size_t)R*E_ + kb;
  else         src = whh + (size_t)R*H_ + ((g*64 + kb - E_) % H_);
  s8v out;
  #pragma unroll
  for (int e = 0; e < 8; e++) out[e] = f2bf(src[e]);
  Apack[idx] = out;
}

// ---------- K1: gather embeddings -> X_all[t][b][256] bf16
__global__ __launch_bounds__(256) void k_embX(
    const int* __restrict__ char_id, const int* __restrict__ bichar_id,
    const float* __restrict__ char_table, const float* __restrict__ bichar_table,
    short* __restrict__ X_all)
{
  int rid  = blockIdx.x*4 + (threadIdx.x>>6);
  int lane = threadIdx.x & 63;
  int t = rid >> 6, b = rid & 63;
  float4 v;
  if (lane < 32) { int c = char_id  [b*T_ + t]; v = *(const float4*)(char_table  + (size_t)c*EMB_ + lane*4); }
  else           { int c = bichar_id[b*T_ + t]; v = *(const float4*)(bichar_table+ (size_t)c*EMB_ + (lane-32)*4); }
  s4v o; o[0]=f2bf(v.x); o[1]=f2bf(v.y); o[2]=f2bf(v.z); o[3]=f2bf(v.w);
  *(s4v*)(X_all + ((size_t)rid*E_ + lane*4)) = o;
}

// ---------- K2: persistent-weight MFMA LSTM; flagless tagged exchange,
// unit-major h layout: producer publishes COALESCED (256 B/wave-instr),
// consumer bursts coalesced (u64 idx = p*512 + tid). Protocol = r13 (verified).
// 48 blocks: dir=bid&1, bg=(bid>>1)&3, g=bid>>3. 512 threads = 8 waves.
__global__ __launch_bounds__(512, 2) void k_lstm_p(
    const s8v* __restrict__ Apack,
    const short* __restrict__ X_all,
    const float* __restrict__ b_f, const float* __restrict__ b_b,
    const float* __restrict__ w_em,
    unsigned* __restrict__ h_slot,      // [2][dir][bg][384 u][16 b] u32=(bf16<<16)|t, init 0xFF
    short* __restrict__ em16)           // [48 pb][512 t][16 b][13 k] bf16
{
  __shared__ char  Xsb[16*XROWB];       // B operand rows=batch: x 0..255, h(rotated) 256..639
  __shared__ short hsl[16][66];         // new h [b][uo]
  __shared__ float wems[K_][64];

  const int bid = blockIdx.x;
  const int dir = bid & 1, bg = (bid>>1)&3, g = bid>>3;
  const int tid = threadIdx.x, lane = tid & 63, w = tid >> 6;
  const int pb  = (dir*NBG+bg)*NG + g;

  // persistent A fragments: 40 s8v = 160 regs (unified VGPR/AGPR file)
  s8v fr0[20], fr1[20];
  {
    const s8v* ap = Apack + ((size_t)((dir*NG+g)*NW + w)*40)*64 + lane;
    #pragma unroll
    for (int kt = 0; kt < 20; kt++) fr0[kt] = ap[kt*64];
    #pragma unroll
    for (int kt = 0; kt < 20; kt++) fr1[kt] = ap[(20+kt)*64];
  }
  for (int i = tid; i < K_*64; i += 512)
    wems[i>>6][i&63] = w_em[(size_t)(i>>6)*(2*H_) + dir*H_ + g*64 + (i&63)];

  const int batch = lane & 15;
  const int uA = w*8 + (lane>>4), uB = uA + 4;    // unit offsets in [0,64)
  const float* bias = dir ? b_b : b_f;
  float bA[4], bB[4];
  #pragma unroll
  for (int r = 0; r < 4; r++) { bA[r] = bias[r*H_ + g*64 + uA]; bB[r] = bias[r*H_ + g*64 + uB]; }
  float cA = 0.f, cB = 0.f;

  const int b_x = tid>>5, kox = (tid&31)*8;       // x-store ownership
  // burst ownership: thread reads u64 #tid of each peer's 512-u64 chunk
  const int u_l = tid >> 3;                       // unit within peer group (0..63)
  const int b0  = (tid & 7) * 2;                  // batch pair
  int pidx[5];                                    // u64 index within slot for each peer
  int posb[5];                                    // rotated Xs unit-position of each peer's u_l
  #pragma unroll
  for (int i = 0; i < 5; i++) {
    int p = (g + 1 + i) % NG;                     // the 5 remote peers
    pidx[i] = p*512 + tid;                        // (p*64+u_l)*16/2 + b0/2 = p*512 + tid
    posb[i] = ((p - g + NG) % NG) * 64 + u_l;     // in [64, 384)
  }

  // zero h region (used at s==0)
  for (int cc = tid; cc < 16*192; cc += 512)
    *(unsigned*)(Xsb + (cc/192)*XROWB + 512 + (cc%192)*4) = 0u;

  s8v xv = *(const s8v*)(X_all + ((size_t)((dir?(T_-1):0)*B_ + bg*16 + b_x)*E_ + kox));
  __syncthreads();

  for (int s = 0; s < T_; s++) {
    const int t  = dir ? (T_-1-s) : s;
    const int tp = dir ? t+1 : t-1;
    const int tn = dir ? t-1 : t+1;

    // 1. store prefetched x(t); prefetch x(next)
    *(s8v*)(Xsb + b_x*XROWB + 2*kox) = xv;
    if (s+1 < T_) xv = *(const s8v*)(X_all + ((size_t)(tn*B_ + bg*16 + b_x)*E_ + kox));

    LBAR();                                       // barrier A

    // 2. emission for previous step (local; reads hsl = h(tp))
    if (s > 0) {
      for (int k = w; k < K_; k += NW) {
        int b = lane>>2, cq = lane&3;
        float acc = 0.f;
        #pragma unroll
        for (int m = 0; m < 8; m++) {
          int u = cq*16 + 2*m;
          unsigned pr = *(const unsigned*)&hsl[b][u];
          acc += bf2f((short)(pr & 0xFFFF)) * wems[k][u]
               + bf2f((short)(pr >> 16))    * wems[k][u+1];
        }
        acc += __shfl_xor(acc, 1, 64);
        acc += __shfl_xor(acc, 2, 64);
        if (cq == 0) em16[((size_t)(pb*T_ + tp)*16 + b)*K_ + k] = f2bf(acc);
      }
    }

    // 3. B1: x (kt 0..7) + own h (kt 8..9) — covers peers' store-travel window
    f4v a0 = {0.f,0.f,0.f,0.f}, a1 = a0;
    #pragma unroll
    for (int kt = 0; kt < 10; kt++) {
      s8v bq = *(const s8v*)(Xsb + (lane&15)*XROWB + kt*64 + (lane>>4)*16);
      a0 = __builtin_amdgcn_mfma_f32_16x16x32_bf16(fr0[kt], bq, a0, 0,0,0);
      a1 = __builtin_amdgcn_mfma_f32_16x16x32_bf16(fr1[kt], bq, a1, 0,0,0);
    }

    // 4. burst: 5 coalesced tagged u64 loads (one per peer); combined-mask retry
    if (s > 0) {
      const unsigned tag = (unsigned)(tp & 0xFFFF);
      const ull tagpair = (ull)tag | ((ull)tag << 32);
      const ull* vb = (const ull*)(h_slot + hslot(tp&1, dir, bg));
      ull v0, v1, v2, v3, v4;
      int tr = 0;
      while (true) {
        v0 = __hip_atomic_load(vb + pidx[0], __ATOMIC_RELAXED, __HIP_MEMORY_SCOPE_AGENT);
        v1 = __hip_atomic_load(vb + pidx[1], __ATOMIC_RELAXED, __HIP_MEMORY_SCOPE_AGENT);
        v2 = __hip_atomic_load(vb + pidx[2], __ATOMIC_RELAXED, __HIP_MEMORY_SCOPE_AGENT);
        v3 = __hip_atomic_load(vb + pidx[3], __ATOMIC_RELAXED, __HIP_MEMORY_SCOPE_AGENT);
        v4 = __hip_atomic_load(vb + pidx[4], __ATOMIC_RELAXED, __HIP_MEMORY_SCOPE_AGENT);
        ull m = (v0^tagpair) | (v1^tagpair) | (v2^tagpair) | (v3^tagpair) | (v4^tagpair);
        if ((m & 0x0000FFFF0000FFFFull) == 0ull) break;
        if (++tr > 16) __builtin_amdgcn_s_sleep(1);
      }
      ull vv[5] = {v0, v1, v2, v3, v4};
      #pragma unroll
      for (int i = 0; i < 5; i++) {
        unsigned lo = (unsigned)vv[i], hi = (unsigned)(vv[i] >> 32);
        *(short*)(Xsb + (b0  )*XROWB + 512 + posb[i]*2) = (short)(lo >> 16);
        *(short*)(Xsb + (b0+1)*XROWB + 512 + posb[i]*2) = (short)(hi >> 16);
      }
    }
    LBAR();                                       // barrier B

    // 5. B2: remote h (kt 10..19)
    #pragma unroll
    for (int kt = 10; kt < 20; kt++) {
      s8v bq = *(const s8v*)(Xsb + (lane&15)*XROWB + kt*64 + (lane>>4)*16);
      a0 = __builtin_amdgcn_mfma_f32_16x16x32_bf16(fr0[kt], bq, a0, 0,0,0);
      a1 = __builtin_amdgcn_mfma_f32_16x16x32_bf16(fr1[kt], bq, a1, 0,0,0);
    }

    // 6. C: in-register nonlinearity (acc[r] = gate r), COALESCED background publish
    {
      cA = sigm(a0[1]+bA[1])*cA + sigm(a0[0]+bA[0])*tanh_f(a0[2]+bA[2]);
      float h0 = sigm(a0[3]+bA[3])*tanh_f(cA);
      cB = sigm(a1[1]+bB[1])*cB + sigm(a1[0]+bB[0])*tanh_f(a1[2]+bB[2]);
      float h1 = sigm(a1[3]+bB[3])*tanh_f(cB);
      short hb0 = f2bf(h0), hb1 = f2bf(h1);
      unsigned vt = (unsigned)(t & 0xFFFF);
      unsigned q0 = ((unsigned)(unsigned short)hb0 << 16) | vt;
      unsigned q1 = ((unsigned)(unsigned short)hb1 << 16) | vt;
      unsigned* hw = h_slot + hslot(t&1, dir, bg);
      // addr = base + (g*64+u)*16 + batch  ->  per-wave lane-consecutive (256 B)
      __hip_atomic_store(hw + (size_t)(g*64 + uA)*16 + batch, q0,
                         __ATOMIC_RELAXED, __HIP_MEMORY_SCOPE_AGENT);
      __hip_atomic_store(hw + (size_t)(g*64 + uB)*16 + batch, q1,
                         __ATOMIC_RELAXED, __HIP_MEMORY_SCOPE_AGENT);
      *(short*)(Xsb + batch*XROWB + 512 + uA*2) = hb0;   // own units = rotated pos 0..63
      *(short*)(Xsb + batch*XROWB + 512 + uB*2) = hb1;
      hsl[batch][uA] = hb0;
      hsl[batch][uB] = hb1;
    }
    // no drain, no flag: stores travel while we loop; consumers tag-verify the data
  }

  // final emission for last step's h
  LBAR();
  {
    const int tl = dir ? 0 : T_-1;
    for (int k = w; k < K_; k += NW) {
      int b = lane>>2, cq = lane&3;
      float acc = 0.f;
      #pragma unroll
      for (int m = 0; m < 8; m++) {
        int u = cq*16 + 2*m;
        unsigned pr = *(const unsigned*)&hsl[b][u];
        acc += bf2f((short)(pr & 0xFFFF)) * wems[k][u]
             + bf2f((short)(pr >> 16))    * wems[k][u+1];
      }
      acc += __shfl_xor(acc, 1, 64);
      acc += __shfl_xor(acc, 2, 64);
      if (cq == 0) em16[((size_t)(pb*T_ + tl)*16 + b)*K_ + k] = f2bf(acc);
    }
  }
}

// ---------- K3: combine 12 partials + bias, log_softmax -> em_out
__global__ __launch_bounds__(256) void k_em2(
    const short* __restrict__ em16, const float* __restrict__ b_em,
    float* __restrict__ em)
{
  int r = blockIdx.x*256 + threadIdx.x;           // b*512 + t
  int b = r >> 9, t = r & 511;
  int bg = b >> 4, b16 = b & 15;
  float e[K_];
  #pragma unroll
  for (int k = 0; k < K_; k++) e[k] = b_em[k];
  #pragma unroll
  for (int dir = 0; dir < 2; dir++)
    for (int g = 0; g < NG; g++) {
      int pb = (dir*NBG+bg)*NG + g;
      const short* p = em16 + ((size_t)(pb*T_ + t)*16 + b16)*K_;
      #pragma unroll
      for (int k = 0; k < K_; k++) e[k] += bf2f(p[k]);
    }
  float mx = -1e30f;
  #pragma unroll
  for (int k = 0; k < K_; k++) mx = fmaxf(mx, e[k]);
  float S = 0.f;
  #pragma unroll
  for (int k = 0; k < K_; k++) S += __expf(e[k]-mx);
  float L = __logf(S) + mx;
  #pragma unroll
  for (int k = 0; k < K_; k++) em[(size_t)r*K_+k] = e[k] - L;
}

// ---------- K4: CRF, wave-synchronous (alpha in lane registers, zero barriers)
__global__ __launch_bounds__(64) void k_crf(
    const int* __restrict__ char_id, const int* __restrict__ label_id,
    const float* __restrict__ em,
    const float* __restrict__ start_trans, const float* __restrict__ end_trans,
    const float* __restrict__ trans, float* __restrict__ llh)
{
  int b = blockIdx.x, lane = threadIdx.x;
  const int*   cid = char_id  + b*T_;
  const int*   tag = label_id + b*T_;
  const float* emb = em + (size_t)b*T_*K_;

  // gold path score (parallel over t) + mask count
  float sc = 0.f; int cntm = 0;
  for (int t = lane; t < T_; t += 64) {
    int m = (cid[t] != 0);
    cntm += m;
    if (t >= 1 && m) sc += trans[tag[t-1]*K_ + tag[t]] + emb[t*K_ + tag[t]];
  }
  #pragma unroll
  for (int off = 32; off; off >>= 1) { sc += __shfl_xor(sc, off, 64); cntm += __shfl_xor(cntm, off, 64); }
  float score = 0.f;
  if (lane == 0) {
    int t0 = tag[0];
    int ce = (cntm > 0) ? (cntm - 1) : 0;
    score = start_trans[t0] + emb[t0] + sc + end_trans[tag[ce]];
  }

  // forward algorithm: lane k holds alpha[k] (k<13); tr_reg[i] = trans[i][k]
  int k = (lane < K_) ? lane : 0;
  float tr_reg[K_];
  #pragma unroll
  for (int i = 0; i < K_; i++) tr_reg[i] = trans[i*K_ + k];
  float alpha = start_trans[k] + emb[k];

  for (int t = 1; t < T_; t++) {
    bool mt = (cid[t] != 0);
    float em_t = emb[t*K_ + k];
    float m = -1e30f, s = 0.f;
    #pragma unroll
    for (int i = 0; i < K_; i++) {
      float v = __shfl(alpha, i, 64) + tr_reg[i];
      float nm = fmaxf(m, v);
      s = s*__expf(m - nm) + __expf(v - nm);
      m = nm;
    }
    float nxt = m + __logf(s) + em_t;
    if (mt) alpha = nxt;
  }

  float v  = (lane < K_) ? alpha + end_trans[lane] : -1e30f;
  float mx = v;
  #pragma unroll
  for (int off = 32; off; off >>= 1) mx = fmaxf(mx, __shfl_xor(mx, off, 64));
  float s2 = __expf(v - mx);
  #pragma unroll
  for (int off = 32; off; off >>= 1) s2 += __shfl_xor(s2, off, 64);
  if (lane == 0) llh[b] = score - (mx + __logf(s2));
}

// ---------- K5: out = -mean(llh)
__global__ __launch_bounds__(64) void k_final(const float* __restrict__ llh, float* __restrict__ out){
  float v = llh[threadIdx.x];
  #pragma unroll
  for (int off = 32; off; off >>= 1) v += __shfl_xor(v, off, 64);
  if (threadIdx.x == 0) out[0] = -v / (float)B_;
}

extern "C" void kernel_launch(void* const* d_in, const int* in_sizes, int n_in,
                              void* d_out, int out_size, void* d_ws, size_t ws_size,
                              hipStream_t stream)
{
  const int*   char_id      = (const int*)  d_in[0];
  const int*   bichar_id    = (const int*)  d_in[1];
  const int*   label_id     = (const int*)  d_in[2];
  const float* char_table   = (const float*)d_in[3];
  const float* bichar_table = (const float*)d_in[4];
  const float* w_ih_f       = (const float*)d_in[5];
  const float* w_hh_f       = (const float*)d_in[6];
  const float* b_f          = (const float*)d_in[7];
  const float* w_ih_b       = (const float*)d_in[8];
  const float* w_hh_b       = (const float*)d_in[9];
  const float* b_b          = (const float*)d_in[10];
  const float* w_em         = (const float*)d_in[11];
  const float* b_em         = (const float*)d_in[12];
  const float* start_trans  = (const float*)d_in[13];
  const float* end_trans    = (const float*)d_in[14];
  const float* trans        = (const float*)d_in[15];

  char* w = (char*)d_ws;
  s8v*      Apack  = (s8v*)w;      w += (size_t)12*NW*2*20*64*16;    //  3,932,160
  short*    X_all  = (short*)w;    w += (size_t)T_*B_*E_*2;          // 16,777,216
  unsigned* h_slot = (unsigned*)w; w += (size_t)2*2*NBG*NG*64*16*4;  //    393,216
  short*    em16   = (short*)w;    w += (size_t)48*T_*16*K_*2;       // 10,223,616
  float*    em_out = (float*)w;    w += (size_t)B_*T_*K_*4;          //  1,703,936
  float*    llh    = (float*)w;    w += 256;
  // total ~33.0 MB

  hipMemsetAsync(h_slot, 0xFF, (size_t)2*2*NBG*NG*64*16*4, stream);

  k_packA<<<960, 256, 0, stream>>>(w_ih_f, w_hh_f, w_ih_b, w_hh_b, Apack);
  k_embX <<<8192, 256, 0, stream>>>(char_id, bichar_id, char_table, bichar_table, X_all);
  k_lstm_p<<<48, 512, 0, stream>>>(Apack, X_all, b_f, b_b, w_em, h_slot, em16);
  k_em2  <<<128, 256, 0, stream>>>(em16, b_em, em_out);
  k_crf  <<<64, 64, 0, stream>>>(char_id, label_id, em_out, start_trans, end_trans, trans, llh);
  k_final<<<1, 64, 0, stream>>>(llh, (float*)d_out);
}